// Round 11
// baseline (128.924 us; speedup 1.0000x reference)
//
#include <hip/hip_runtime.h>
#include <stdint.h>

#define OBS 15
#define NTOT 50000
#define HDIM 64
#define NPB 16      // neighbors per block (50000 = 3125 * 16, exact)
#define NBLK_N 3125 // neighbor blocks; blockIdx 0 runs the target LSTM

typedef __attribute__((ext_vector_type(8))) short short8;
typedef __attribute__((ext_vector_type(4))) float f32x4;
typedef __attribute__((ext_vector_type(4))) unsigned int u32x4;

#define KLOG2E 1.4426950408889634f   // log2(e)
#define KLOG2E2 2.8853900817779268f  // 2*log2(e)

static __device__ __forceinline__ unsigned short f2bf(float f) {
  unsigned u = __float_as_uint(f);
  u += 0x7fff + ((u >> 16) & 1);
  return (unsigned short)(u >> 16);
}

// RNE pack of two f32 -> 2 bf16 in one VALU inst (low short = first arg).
static __device__ __forceinline__ unsigned cvtpk_bf16(float lo, float hi) {
  unsigned r;
  asm("v_cvt_pk_bf16_f32 %0, %1, %2" : "=v"(r) : "v"(lo), "v"(hi));
  return r;
}

#if __has_builtin(__builtin_amdgcn_exp2f)
#define EXP2F(x) __builtin_amdgcn_exp2f(x)
#else
#define EXP2F(x) exp2f(x)
#endif
#if __has_builtin(__builtin_amdgcn_rcpf)
#define RCPF(x) __builtin_amdgcn_rcpf(x)
#else
#define RCPF(x) (1.0f / (x))
#endif

static __device__ __forceinline__ float sigm(float x) {
  return RCPF(1.0f + EXP2F(-KLOG2E * x));
}
static __device__ __forceinline__ float tanh_(float x) {
  return 2.0f * RCPF(1.0f + EXP2F(-KLOG2E2 * x)) - 1.0f;
}

// LDS ushort index: row r (0..15), 8-ushort block cb (0..7), swizzled.
static __device__ __forceinline__ int hidx(int r, int cb) {
  return r * 64 + ((cb ^ (r & 7)) << 3);
}

#define MFMA_BF16 __builtin_amdgcn_mfma_f32_16x16x32_bf16

// ROUND-11: drop the W lo-correction plane.
// Rationale (counter-driven): issue is ~71% full (VALU 54 + MFMA 17); half the
// MFMA chain (8 Blo corrections/step) removes a W-quantization error that is
// the SAME magnitude as the h bf16-quantization error already accepted
// (both ~6e-4 at the gate), and pooling over ~1000s of neighbors averages it
// down.  Dropping it: 16->8 MFMAs/step, W frags 64->32 regs.
// The register cut re-opens occupancy BELOW the spill cliff: (256,3) budget
// ~170 regs vs live ~128 — wide margin, unlike (256,4) which spilled twice
// (r8: 127 MB, r9: 27 MB scratch writes).  3 waves/SIMD = +50% TLP.
// Also: LOADB via v_cvt_pk_bf16_f32 (2 values/inst, RNE — same rounding as
// f2bf) cuts the conversion prologue ~1900 -> ~100 insts/wave (~16 us of
// VALU-busy across the kernel was prologue).
// Kept from r10 (all verified): pre-scaled gates (exp2 domain), cs-domain
// single-rcp cell, xs float staging (0 bank conflicts), target-LSTM at
// blockIdx 0, slim k_final, memset social.
// Tripwires: passed=false -> restore lo plane + (256,2) next round;
// WRITE_SIZE >> 2.5 MB -> spill, same revert.
__global__ __launch_bounds__(256, 3)
void k_neigh(
    const float* __restrict__ tgt,   // 15*1*2
    const float* __restrict__ oth,   // 15*N*2
    const int* __restrict__ mask,    // 15*N
    const float* __restrict__ W_ih,  // 256*2
    const float* __restrict__ b_ih,  // 256
    const float* __restrict__ W_hh,  // 256*64
    const float* __restrict__ b_hh,  // 256
    float* __restrict__ social,      // 16*64, pre-zeroed
    float* __restrict__ ht_out)      // 64 (target-LSTM final h)
{
  __shared__ __align__(16) unsigned short h2[2][NPB][HDIM];  // h as bf16
  __shared__ float xs[OBS][NPB][2];
  __shared__ float tht[HDIM];
  __shared__ float tgb[256];

  const int tid = threadIdx.x;

  if (blockIdx.x == 0) {
    // ---- target LSTM, fp32 exact (raw unscaled weights); dispatched FIRST
    // so it hides under the neighbor grid.  Block-uniform branch.
    const float bias = b_ih[tid] + b_hh[tid];
    const float wi0 = W_ih[tid * 2], wi1 = W_ih[tid * 2 + 1];
    const float4* Wr = (const float4*)&W_hh[tid * 64];
    if (tid < HDIM) tht[tid] = 0.0f;
    float ct = 0.0f;
    __syncthreads();
    for (int t = 0; t < OBS; ++t) {
      const float x0 = tgt[t * 2], x1 = tgt[t * 2 + 1];
      float acc = bias + x0 * wi0 + x1 * wi1;
#pragma unroll 4
      for (int k4 = 0; k4 < 16; ++k4) {
        const float4 wv = Wr[k4];
        const float4 hv = *(const float4*)&tht[k4 * 4];
        acc += wv.x * hv.x + wv.y * hv.y + wv.z * hv.z + wv.w * hv.w;
      }
      tgb[tid] = acc;
      __syncthreads();
      if (tid < HDIM) {
        const float cn =
            sigm(tgb[64 + tid]) * ct + sigm(tgb[tid]) * tanh_(tgb[128 + tid]);
        ct = cn;
        tht[tid] = sigm(tgb[192 + tid]) * tanh_(cn);
      }
      __syncthreads();
    }
    if (tid < HDIM) ht_out[tid] = tht[tid];
    return;
  }

  const int l = tid & 63;
  const int w = tid >> 6;   // wave id 0..3 -> owns gate-col slice w*16..w*16+15
  const int t15 = l & 15;
  const int g4 = l >> 4;
  const int n0 = (blockIdx.x - 1) * NPB;

  // stage xo for this block's 16 neighbors, all steps (coalesced, no tail)
  for (int i = tid; i < OBS * NPB * 2; i += 256) {
    ((float*)xs)[i] = oth[(i >> 5) * (NTOT * 2) + n0 * 2 + (i & 31)];
  }
  // zero h buffer 0
  for (int i = tid; i < NPB * HDIM / 2; i += 256) ((unsigned int*)h2[0])[i] = 0u;

  // persistent B fragments: W_hh^T slices for this wave's gate cols,
  // PRE-SCALED by the consuming activation's exp2 constant, single bf16 RNE
  // (lo plane dropped this round), packed 2-per-inst via v_cvt_pk_bf16_f32.
  short8 Bhi0, Bhi1, Bhi2, Bhi3, Bhi4, Bhi5, Bhi6, Bhi7;
#define LOADB(q, kt, BH, SC)                                                  \
  {                                                                           \
    const float* wp = &W_hh[(q * 64 + w * 16 + t15) * 64 + kt * 32 + g4 * 8]; \
    u32x4 d;                                                                  \
    d.x = cvtpk_bf16(wp[0] * (SC), wp[1] * (SC));                             \
    d.y = cvtpk_bf16(wp[2] * (SC), wp[3] * (SC));                             \
    d.z = cvtpk_bf16(wp[4] * (SC), wp[5] * (SC));                             \
    d.w = cvtpk_bf16(wp[6] * (SC), wp[7] * (SC));                             \
    BH = __builtin_bit_cast(short8, d);                                       \
  }
  LOADB(0, 0, Bhi0, -KLOG2E)  LOADB(0, 1, Bhi1, -KLOG2E)
  LOADB(1, 0, Bhi2, -KLOG2E)  LOADB(1, 1, Bhi3, -KLOG2E)
  LOADB(2, 0, Bhi4, -KLOG2E2) LOADB(2, 1, Bhi5, -KLOG2E2)
  LOADB(3, 0, Bhi6, -KLOG2E)  LOADB(3, 1, Bhi7, -KLOG2E)
#undef LOADB

  // VALU acc-init constants, PRE-SCALED (gates live in the exp2 domain).
  float bias2[4], wih0[4], wih1[4];
#pragma unroll
  for (int q = 0; q < 4; ++q) {
    const float sc = (q == 2) ? -KLOG2E2 : -KLOG2E;
    const int g = q * 64 + w * 16 + t15;
    bias2[q] = (b_ih[g] + b_hh[g]) * sc;
    wih0[q] = W_ih[g * 2 + 0] * sc;
    wih1[q] = W_ih[g * 2 + 1] * sc;
  }

  // cs = -2log2e * c  (c starts at 0)
  f32x4 cs = (f32x4){0.f, 0.f, 0.f, 0.f};
  const float refx = tgt[14 * 2 + 0];
  const float refy = tgt[14 * 2 + 1];

  __syncthreads();

  for (int t = 0; t < OBS; ++t) {
    const int cur = t & 1, nxt = cur ^ 1;
    // A fragments: row t15, k-block (kt*4 + g4), direct bf16 LDS read
    short8 A0 = *(const short8*)&h2[cur][0][hidx(t15, g4)];
    short8 A1 = *(const short8*)&h2[cur][0][hidx(t15, 4 + g4)];

    // acc0 = -log2e*i, acc1 = -log2e*f, acc2 = -2log2e*g, acc3 = -log2e*o
    f32x4 acc0, acc1, acc2, acc3;
#pragma unroll
    for (int r = 0; r < 4; ++r) {
      const int nl = g4 * 4 + r;
      const float xa = xs[t][nl][0], xb = xs[t][nl][1];
      acc0[r] = bias2[0] + xa * wih0[0] + xb * wih1[0];
      acc1[r] = bias2[1] + xa * wih0[1] + xb * wih1[1];
      acc2[r] = bias2[2] + xa * wih0[2] + xb * wih1[2];
      acc3[r] = bias2[3] + xa * wih0[3] + xb * wih1[3];
    }
    acc0 = MFMA_BF16(A0, Bhi0, acc0, 0, 0, 0);
    acc1 = MFMA_BF16(A0, Bhi2, acc1, 0, 0, 0);
    acc2 = MFMA_BF16(A0, Bhi4, acc2, 0, 0, 0);
    acc3 = MFMA_BF16(A0, Bhi6, acc3, 0, 0, 0);
    acc0 = MFMA_BF16(A1, Bhi1, acc0, 0, 0, 0);
    acc1 = MFMA_BF16(A1, Bhi3, acc1, 0, 0, 0);
    acc2 = MFMA_BF16(A1, Bhi5, acc2, 0, 0, 0);
    acc3 = MFMA_BF16(A1, Bhi7, acc3, 0, 0, 0);

    // cs-domain fused cell (A=1+ei, B=1+eg, C=1+ef):
    //   cs' = (cs*A*B + K2*(eg-1)*C) * rcp(A*B*C)   [= -2log2e * cn]
    //   ecn = exp2(cs')
    //   h   = (1-ecn) / ((1+eo)(1+ecn))             [= sig(o)*tanh(cn)]
    if (t < OBS - 1) {
#pragma unroll
      for (int r = 0; r < 4; ++r) {
        const float ei = EXP2F(acc0[r]);
        const float ef = EXP2F(acc1[r]);
        const float eg = EXP2F(acc2[r]);
        const float eo = EXP2F(acc3[r]);
        const float A = 1.0f + ei, B = 1.0f + eg, C = 1.0f + ef;
        const float AB = A * B;
        const float rr = RCPF(AB * C);
        const float u = (eg - 1.0f) * C;
        const float csn = (cs[r] * AB + KLOG2E2 * u) * rr;
        cs[r] = csn;
        const float ecn = EXP2F(csn);
        const float ro = RCPF((1.0f + eo) * (1.0f + ecn));
        const float h = (1.0f - ecn) * ro;
        const int n = g4 * 4 + r;
        const int col = w * 16 + t15;
        h2[nxt][0][hidx(n, col >> 3) + (col & 7)] = f2bf(h);
      }
      __syncthreads();
    } else {
      // final step: compute h (fp32) and pool directly
#pragma unroll
      for (int r = 0; r < 4; ++r) {
        const float ei = EXP2F(acc0[r]);
        const float ef = EXP2F(acc1[r]);
        const float eg = EXP2F(acc2[r]);
        const float eo = EXP2F(acc3[r]);
        const float A = 1.0f + ei, B = 1.0f + eg, C = 1.0f + ef;
        const float AB = A * B;
        const float rr = RCPF(AB * C);
        const float u = (eg - 1.0f) * C;
        const float csn = (cs[r] * AB + KLOG2E2 * u) * rr;
        const float ecn = EXP2F(csn);
        const float ro = RCPF((1.0f + eo) * (1.0f + ecn));
        const float h = (1.0f - ecn) * ro;
        const int nl = g4 * 4 + r;
        const int gn = n0 + nl;
        const float rx = xs[OBS - 1][nl][0] - refx;
        const float ry = xs[OBS - 1][nl][1] - refy;
        bool ok = (fabsf(rx) <= 2.0f) && (fabsf(ry) <= 2.0f);
        const int cx = (int)truncf(rx) + 2;  // cw == 1.0
        const int cy = (int)truncf(ry) + 2;
        ok = ok && (cx >= 0) && (cx < 4) && (cy >= 0) && (cy < 4);
        if (ok && mask[(OBS - 1) * NTOT + gn] != 0)
          atomicAdd(&social[(cy * 4 + cx) * HDIM + w * 16 + t15], h);
      }
    }
  }
}

// Slim k_final (verified rounds 1-10): social MLP + readout only.
__global__ __launch_bounds__(512) void k_final(
    const float* __restrict__ W1, const float* __restrict__ b1,
    const float* __restrict__ W2, const float* __restrict__ b2,
    const float* __restrict__ Wc, const float* __restrict__ bc,
    const float* __restrict__ social, const float* __restrict__ ht_g,
    float* __restrict__ out)
{
  __shared__ float sv[1024];
  __shared__ float hid[64];
  __shared__ float comb[64];
  __shared__ float ht[64];

  const int tid = threadIdx.x;
  for (int i = tid; i < 1024; i += 512) sv[i] = social[i];
  if (tid < 64) ht[tid] = ht_g[tid];
  __syncthreads();

  const int wv = tid >> 6, ln = tid & 63;
  for (int o = wv; o < 64; o += 8) {
    float p = 0.0f;
#pragma unroll
    for (int it = 0; it < 16; ++it) {
      const int j = it * 64 + ln;
      p += sv[j] * W1[o * 1024 + j];
    }
#pragma unroll
    for (int off = 32; off > 0; off >>= 1) p += __shfl_down(p, off);
    if (ln == 0) hid[o] = fmaxf(p + b1[o], 0.0f);
  }
  __syncthreads();
  for (int o = wv; o < 64; o += 8) {
    float p = hid[ln] * W2[o * 64 + ln];
#pragma unroll
    for (int off = 32; off > 0; off >>= 1) p += __shfl_down(p, off);
    if (ln == 0) comb[o] = ht[o] + p + b2[o];
  }
  __syncthreads();
  if (wv < 2) {
    float p = comb[ln] * Wc[wv * 64 + ln];
#pragma unroll
    for (int off = 32; off > 0; off >>= 1) p += __shfl_down(p, off);
    if (ln == 0) out[wv] = p + bc[wv];
  }
}

extern "C" void kernel_launch(void* const* d_in, const int* in_sizes, int n_in,
                              void* d_out, int out_size, void* d_ws, size_t ws_size,
                              hipStream_t stream) {
  const float* tgt = (const float*)d_in[0];
  const float* oth = (const float*)d_in[1];
  const int* mask = (const int*)d_in[2];
  const float* W_ih = (const float*)d_in[3];
  const float* b_ih = (const float*)d_in[4];
  const float* W_hh = (const float*)d_in[5];
  const float* b_hh = (const float*)d_in[6];
  const float* W1 = (const float*)d_in[7];
  const float* b1 = (const float*)d_in[8];
  const float* W2 = (const float*)d_in[9];
  const float* b2 = (const float*)d_in[10];
  const float* Wc = (const float*)d_in[11];
  const float* bc = (const float*)d_in[12];
  float* social = (float*)d_ws;          // ws[0..1023]
  float* ht = social + 1024;             // ws[1024..1087] (target-LSTM h)
  float* out = (float*)d_out;

  // social zeroed via memset node (graph-capturable; harness reset() uses it)
  hipMemsetAsync(social, 0, 16 * 64 * sizeof(float), stream);
  hipLaunchKernelGGL(k_neigh, dim3(NBLK_N + 1), dim3(256), 0, stream,
                     tgt, oth, mask, W_ih, b_ih, W_hh, b_hh, social, ht);
  hipLaunchKernelGGL(k_final, dim3(1), dim3(512), 0, stream,
                     W1, b1, W2, b2, Wc, bc, social, ht, out);
}

// Round 12
// 128.519 us; speedup vs baseline: 1.0032x; 1.0032x over previous
//
#include <hip/hip_runtime.h>
#include <stdint.h>

#define OBS 15
#define NTOT 50000
#define HDIM 64
#define NPB 16      // neighbors per block (50000 = 3125 * 16, exact)
#define NBLK_N 3125 // neighbor blocks; blockIdx 0 runs the target LSTM

typedef __attribute__((ext_vector_type(8))) short short8;
typedef __attribute__((ext_vector_type(4))) float f32x4;
typedef __attribute__((ext_vector_type(4))) unsigned int u32x4;

#define KLOG2E 1.4426950408889634f   // log2(e)
#define KLOG2E2 2.8853900817779268f  // 2*log2(e)

static __device__ __forceinline__ unsigned short f2bf(float f) {
  unsigned u = __float_as_uint(f);
  u += 0x7fff + ((u >> 16) & 1);
  return (unsigned short)(u >> 16);
}

// RNE pack of two f32 -> 2 bf16 in one VALU inst (low short = first arg).
static __device__ __forceinline__ unsigned cvtpk_bf16(float lo, float hi) {
  unsigned r;
  asm("v_cvt_pk_bf16_f32 %0, %1, %2" : "=v"(r) : "v"(lo), "v"(hi));
  return r;
}

#if __has_builtin(__builtin_amdgcn_exp2f)
#define EXP2F(x) __builtin_amdgcn_exp2f(x)
#else
#define EXP2F(x) exp2f(x)
#endif
#if __has_builtin(__builtin_amdgcn_rcpf)
#define RCPF(x) __builtin_amdgcn_rcpf(x)
#else
#define RCPF(x) (1.0f / (x))
#endif

static __device__ __forceinline__ float sigm(float x) {
  return RCPF(1.0f + EXP2F(-KLOG2E * x));
}
static __device__ __forceinline__ float tanh_(float x) {
  return 2.0f * RCPF(1.0f + EXP2F(-KLOG2E2 * x)) - 1.0f;
}

// LDS ushort index: row r (0..15), 8-ushort block cb (0..7), swizzled.
static __device__ __forceinline__ int hidx(int r, int cb) {
  return r * 64 + ((cb ^ (r & 7)) << 3);
}

#define MFMA_BF16 __builtin_amdgcn_mfma_f32_16x16x32_bf16

// ROUND-12 SINGLE-VARIABLE EXPERIMENT on the r11 kernel: (256,3) -> (256,4).
// r11 established: single-bf16 W passes (absmax 0.0) at HALF the MFMA chain
// and W frags 64->32 regs; total allocation is now 56 regs.  The (256,4)
// split (64 arch + 64 acc per wave) that spilled at r8 (live ~68 arch) and
// r9 (~60) now has ~24 regs of headroom — live arch ~40.  4 waves/SIMD =
// +33% TLP vs r11 against a latency-bound profile (HBM 0.6%, MfmaUtil 8%,
// VALUBusy 44%).  Tripwire: WRITE_SIZE >> 2.5 MB = spill -> revert and
// conclude at the session's best-timed configuration.
__global__ __launch_bounds__(256, 4)
void k_neigh(
    const float* __restrict__ tgt,   // 15*1*2
    const float* __restrict__ oth,   // 15*N*2
    const int* __restrict__ mask,    // 15*N
    const float* __restrict__ W_ih,  // 256*2
    const float* __restrict__ b_ih,  // 256
    const float* __restrict__ W_hh,  // 256*64
    const float* __restrict__ b_hh,  // 256
    float* __restrict__ social,      // 16*64, pre-zeroed
    float* __restrict__ ht_out)      // 64 (target-LSTM final h)
{
  __shared__ __align__(16) unsigned short h2[2][NPB][HDIM];  // h as bf16
  __shared__ float xs[OBS][NPB][2];
  __shared__ float tht[HDIM];
  __shared__ float tgb[256];

  const int tid = threadIdx.x;

  if (blockIdx.x == 0) {
    // ---- target LSTM, fp32 exact (raw unscaled weights); dispatched FIRST
    // so it hides under the neighbor grid.  Block-uniform branch.
    const float bias = b_ih[tid] + b_hh[tid];
    const float wi0 = W_ih[tid * 2], wi1 = W_ih[tid * 2 + 1];
    const float4* Wr = (const float4*)&W_hh[tid * 64];
    if (tid < HDIM) tht[tid] = 0.0f;
    float ct = 0.0f;
    __syncthreads();
    for (int t = 0; t < OBS; ++t) {
      const float x0 = tgt[t * 2], x1 = tgt[t * 2 + 1];
      float acc = bias + x0 * wi0 + x1 * wi1;
#pragma unroll 4
      for (int k4 = 0; k4 < 16; ++k4) {
        const float4 wv = Wr[k4];
        const float4 hv = *(const float4*)&tht[k4 * 4];
        acc += wv.x * hv.x + wv.y * hv.y + wv.z * hv.z + wv.w * hv.w;
      }
      tgb[tid] = acc;
      __syncthreads();
      if (tid < HDIM) {
        const float cn =
            sigm(tgb[64 + tid]) * ct + sigm(tgb[tid]) * tanh_(tgb[128 + tid]);
        ct = cn;
        tht[tid] = sigm(tgb[192 + tid]) * tanh_(cn);
      }
      __syncthreads();
    }
    if (tid < HDIM) ht_out[tid] = tht[tid];
    return;
  }

  const int l = tid & 63;
  const int w = tid >> 6;   // wave id 0..3 -> owns gate-col slice w*16..w*16+15
  const int t15 = l & 15;
  const int g4 = l >> 4;
  const int n0 = (blockIdx.x - 1) * NPB;

  // stage xo for this block's 16 neighbors, all steps (coalesced, no tail)
  for (int i = tid; i < OBS * NPB * 2; i += 256) {
    ((float*)xs)[i] = oth[(i >> 5) * (NTOT * 2) + n0 * 2 + (i & 31)];
  }
  // zero h buffer 0
  for (int i = tid; i < NPB * HDIM / 2; i += 256) ((unsigned int*)h2[0])[i] = 0u;

  // persistent B fragments: W_hh^T slices for this wave's gate cols,
  // PRE-SCALED by the consuming activation's exp2 constant, single bf16 RNE
  // (lo plane dropped in r11, verified passing), packed via v_cvt_pk_bf16_f32.
  short8 Bhi0, Bhi1, Bhi2, Bhi3, Bhi4, Bhi5, Bhi6, Bhi7;
#define LOADB(q, kt, BH, SC)                                                  \
  {                                                                           \
    const float* wp = &W_hh[(q * 64 + w * 16 + t15) * 64 + kt * 32 + g4 * 8]; \
    u32x4 d;                                                                  \
    d.x = cvtpk_bf16(wp[0] * (SC), wp[1] * (SC));                             \
    d.y = cvtpk_bf16(wp[2] * (SC), wp[3] * (SC));                             \
    d.z = cvtpk_bf16(wp[4] * (SC), wp[5] * (SC));                             \
    d.w = cvtpk_bf16(wp[6] * (SC), wp[7] * (SC));                             \
    BH = __builtin_bit_cast(short8, d);                                       \
  }
  LOADB(0, 0, Bhi0, -KLOG2E)  LOADB(0, 1, Bhi1, -KLOG2E)
  LOADB(1, 0, Bhi2, -KLOG2E)  LOADB(1, 1, Bhi3, -KLOG2E)
  LOADB(2, 0, Bhi4, -KLOG2E2) LOADB(2, 1, Bhi5, -KLOG2E2)
  LOADB(3, 0, Bhi6, -KLOG2E)  LOADB(3, 1, Bhi7, -KLOG2E)
#undef LOADB

  // VALU acc-init constants, PRE-SCALED (gates live in the exp2 domain).
  float bias2[4], wih0[4], wih1[4];
#pragma unroll
  for (int q = 0; q < 4; ++q) {
    const float sc = (q == 2) ? -KLOG2E2 : -KLOG2E;
    const int g = q * 64 + w * 16 + t15;
    bias2[q] = (b_ih[g] + b_hh[g]) * sc;
    wih0[q] = W_ih[g * 2 + 0] * sc;
    wih1[q] = W_ih[g * 2 + 1] * sc;
  }

  // cs = -2log2e * c  (c starts at 0)
  f32x4 cs = (f32x4){0.f, 0.f, 0.f, 0.f};
  const float refx = tgt[14 * 2 + 0];
  const float refy = tgt[14 * 2 + 1];

  __syncthreads();

  for (int t = 0; t < OBS; ++t) {
    const int cur = t & 1, nxt = cur ^ 1;
    // A fragments: row t15, k-block (kt*4 + g4), direct bf16 LDS read
    short8 A0 = *(const short8*)&h2[cur][0][hidx(t15, g4)];
    short8 A1 = *(const short8*)&h2[cur][0][hidx(t15, 4 + g4)];

    // acc0 = -log2e*i, acc1 = -log2e*f, acc2 = -2log2e*g, acc3 = -log2e*o
    f32x4 acc0, acc1, acc2, acc3;
#pragma unroll
    for (int r = 0; r < 4; ++r) {
      const int nl = g4 * 4 + r;
      const float xa = xs[t][nl][0], xb = xs[t][nl][1];
      acc0[r] = bias2[0] + xa * wih0[0] + xb * wih1[0];
      acc1[r] = bias2[1] + xa * wih0[1] + xb * wih1[1];
      acc2[r] = bias2[2] + xa * wih0[2] + xb * wih1[2];
      acc3[r] = bias2[3] + xa * wih0[3] + xb * wih1[3];
    }
    acc0 = MFMA_BF16(A0, Bhi0, acc0, 0, 0, 0);
    acc1 = MFMA_BF16(A0, Bhi2, acc1, 0, 0, 0);
    acc2 = MFMA_BF16(A0, Bhi4, acc2, 0, 0, 0);
    acc3 = MFMA_BF16(A0, Bhi6, acc3, 0, 0, 0);
    acc0 = MFMA_BF16(A1, Bhi1, acc0, 0, 0, 0);
    acc1 = MFMA_BF16(A1, Bhi3, acc1, 0, 0, 0);
    acc2 = MFMA_BF16(A1, Bhi5, acc2, 0, 0, 0);
    acc3 = MFMA_BF16(A1, Bhi7, acc3, 0, 0, 0);

    // cs-domain fused cell (A=1+ei, B=1+eg, C=1+ef):
    //   cs' = (cs*A*B + K2*(eg-1)*C) * rcp(A*B*C)   [= -2log2e * cn]
    //   ecn = exp2(cs')
    //   h   = (1-ecn) / ((1+eo)(1+ecn))             [= sig(o)*tanh(cn)]
    if (t < OBS - 1) {
#pragma unroll
      for (int r = 0; r < 4; ++r) {
        const float ei = EXP2F(acc0[r]);
        const float ef = EXP2F(acc1[r]);
        const float eg = EXP2F(acc2[r]);
        const float eo = EXP2F(acc3[r]);
        const float A = 1.0f + ei, B = 1.0f + eg, C = 1.0f + ef;
        const float AB = A * B;
        const float rr = RCPF(AB * C);
        const float u = (eg - 1.0f) * C;
        const float csn = (cs[r] * AB + KLOG2E2 * u) * rr;
        cs[r] = csn;
        const float ecn = EXP2F(csn);
        const float ro = RCPF((1.0f + eo) * (1.0f + ecn));
        const float h = (1.0f - ecn) * ro;
        const int n = g4 * 4 + r;
        const int col = w * 16 + t15;
        h2[nxt][0][hidx(n, col >> 3) + (col & 7)] = f2bf(h);
      }
      __syncthreads();
    } else {
      // final step: compute h (fp32) and pool directly
#pragma unroll
      for (int r = 0; r < 4; ++r) {
        const float ei = EXP2F(acc0[r]);
        const float ef = EXP2F(acc1[r]);
        const float eg = EXP2F(acc2[r]);
        const float eo = EXP2F(acc3[r]);
        const float A = 1.0f + ei, B = 1.0f + eg, C = 1.0f + ef;
        const float AB = A * B;
        const float rr = RCPF(AB * C);
        const float u = (eg - 1.0f) * C;
        const float csn = (cs[r] * AB + KLOG2E2 * u) * rr;
        const float ecn = EXP2F(csn);
        const float ro = RCPF((1.0f + eo) * (1.0f + ecn));
        const float h = (1.0f - ecn) * ro;
        const int nl = g4 * 4 + r;
        const int gn = n0 + nl;
        const float rx = xs[OBS - 1][nl][0] - refx;
        const float ry = xs[OBS - 1][nl][1] - refy;
        bool ok = (fabsf(rx) <= 2.0f) && (fabsf(ry) <= 2.0f);
        const int cx = (int)truncf(rx) + 2;  // cw == 1.0
        const int cy = (int)truncf(ry) + 2;
        ok = ok && (cx >= 0) && (cx < 4) && (cy >= 0) && (cy < 4);
        if (ok && mask[(OBS - 1) * NTOT + gn] != 0)
          atomicAdd(&social[(cy * 4 + cx) * HDIM + w * 16 + t15], h);
      }
    }
  }
}

// Slim k_final (verified rounds 1-11): social MLP + readout only.
__global__ __launch_bounds__(512) void k_final(
    const float* __restrict__ W1, const float* __restrict__ b1,
    const float* __restrict__ W2, const float* __restrict__ b2,
    const float* __restrict__ Wc, const float* __restrict__ bc,
    const float* __restrict__ social, const float* __restrict__ ht_g,
    float* __restrict__ out)
{
  __shared__ float sv[1024];
  __shared__ float hid[64];
  __shared__ float comb[64];
  __shared__ float ht[64];

  const int tid = threadIdx.x;
  for (int i = tid; i < 1024; i += 512) sv[i] = social[i];
  if (tid < 64) ht[tid] = ht_g[tid];
  __syncthreads();

  const int wv = tid >> 6, ln = tid & 63;
  for (int o = wv; o < 64; o += 8) {
    float p = 0.0f;
#pragma unroll
    for (int it = 0; it < 16; ++it) {
      const int j = it * 64 + ln;
      p += sv[j] * W1[o * 1024 + j];
    }
#pragma unroll
    for (int off = 32; off > 0; off >>= 1) p += __shfl_down(p, off);
    if (ln == 0) hid[o] = fmaxf(p + b1[o], 0.0f);
  }
  __syncthreads();
  for (int o = wv; o < 64; o += 8) {
    float p = hid[ln] * W2[o * 64 + ln];
#pragma unroll
    for (int off = 32; off > 0; off >>= 1) p += __shfl_down(p, off);
    if (ln == 0) comb[o] = ht[o] + p + b2[o];
  }
  __syncthreads();
  if (wv < 2) {
    float p = comb[ln] * Wc[wv * 64 + ln];
#pragma unroll
    for (int off = 32; off > 0; off >>= 1) p += __shfl_down(p, off);
    if (ln == 0) out[wv] = p + bc[wv];
  }
}

extern "C" void kernel_launch(void* const* d_in, const int* in_sizes, int n_in,
                              void* d_out, int out_size, void* d_ws, size_t ws_size,
                              hipStream_t stream) {
  const float* tgt = (const float*)d_in[0];
  const float* oth = (const float*)d_in[1];
  const int* mask = (const int*)d_in[2];
  const float* W_ih = (const float*)d_in[3];
  const float* b_ih = (const float*)d_in[4];
  const float* W_hh = (const float*)d_in[5];
  const float* b_hh = (const float*)d_in[6];
  const float* W1 = (const float*)d_in[7];
  const float* b1 = (const float*)d_in[8];
  const float* W2 = (const float*)d_in[9];
  const float* b2 = (const float*)d_in[10];
  const float* Wc = (const float*)d_in[11];
  const float* bc = (const float*)d_in[12];
  float* social = (float*)d_ws;          // ws[0..1023]
  float* ht = social + 1024;             // ws[1024..1087] (target-LSTM h)
  float* out = (float*)d_out;

  // social zeroed via memset node (graph-capturable; harness reset() uses it)
  hipMemsetAsync(social, 0, 16 * 64 * sizeof(float), stream);
  hipLaunchKernelGGL(k_neigh, dim3(NBLK_N + 1), dim3(256), 0, stream,
                     tgt, oth, mask, W_ih, b_ih, W_hh, b_hh, social, ht);
  hipLaunchKernelGGL(k_final, dim3(1), dim3(512), 0, stream,
                     W1, b1, W2, b2, Wc, bc, social, ht, out);
}

// Round 13
// 127.997 us; speedup vs baseline: 1.0072x; 1.0041x over previous
//
#include <hip/hip_runtime.h>
#include <stdint.h>

#define OBS 15
#define NTOT 50000
#define HDIM 64
#define NPB 16      // neighbors per block (50000 = 3125 * 16, exact)
#define NBLK_N 3125 // neighbor blocks; blockIdx 0 runs the target LSTM

typedef __attribute__((ext_vector_type(8))) short short8;
typedef __attribute__((ext_vector_type(4))) float f32x4;
typedef __attribute__((ext_vector_type(2))) float f32x2;
typedef __attribute__((ext_vector_type(4))) unsigned int u32x4;

#define KLOG2E 1.4426950408889634f   // log2(e)
#define KLOG2E2 2.8853900817779268f  // 2*log2(e)

static __device__ __forceinline__ unsigned short f2bf(float f) {
  unsigned u = __float_as_uint(f);
  u += 0x7fff + ((u >> 16) & 1);
  return (unsigned short)(u >> 16);
}

// RNE pack of two f32 -> 2 bf16 in one VALU inst (low short = first arg).
static __device__ __forceinline__ unsigned cvtpk_bf16(float lo, float hi) {
  unsigned r;
  asm("v_cvt_pk_bf16_f32 %0, %1, %2" : "=v"(r) : "v"(lo), "v"(hi));
  return r;
}

#if __has_builtin(__builtin_amdgcn_exp2f)
#define EXP2F(x) __builtin_amdgcn_exp2f(x)
#else
#define EXP2F(x) exp2f(x)
#endif
#if __has_builtin(__builtin_amdgcn_rcpf)
#define RCPF(x) __builtin_amdgcn_rcpf(x)
#else
#define RCPF(x) (1.0f / (x))
#endif

static __device__ __forceinline__ float sigm(float x) {
  return RCPF(1.0f + EXP2F(-KLOG2E * x));
}
static __device__ __forceinline__ float tanh_(float x) {
  return 2.0f * RCPF(1.0f + EXP2F(-KLOG2E2 * x)) - 1.0f;
}

// element-wise helpers on f32x2 (clang ext-vectors: ops map to <2 x float> IR,
// which AMDGPU lowers to v_pk_{add,mul,fma}_f32 on gfx90a+; worst case it
// scalarizes to the identical op sequence — numerics unchanged either way)
static __device__ __forceinline__ f32x2 exp2v(f32x2 a) {
  f32x2 r; r.x = EXP2F(a.x); r.y = EXP2F(a.y); return r;
}
static __device__ __forceinline__ f32x2 rcpv(f32x2 a) {
  f32x2 r; r.x = RCPF(a.x); r.y = RCPF(a.y); return r;
}

// LDS ushort index: row r (0..15), 8-ushort block cb (0..7), swizzled.
static __device__ __forceinline__ int hidx(int r, int cb) {
  return r * 64 + ((cb ^ (r & 7)) << 3);
}

#define MFMA_BF16 __builtin_amdgcn_mfma_f32_16x16x32_bf16

// ROUND-13 FINAL CONFIGURATION.  Session evidence:
//  - Timed metric (gold) favors (256,2): best-timed kernels r6=120.5/r10=123.4
//    are both (256,2); all (256,3)/(256,4) variants time 128-129 despite
//    profiled k_neigh improving to 112 (occupancy arc CLOSED on timed data).
//  - Single-bf16 W (r11/r12, absmax 0.0): half the MFMA chain, W frags 32 regs.
//  - cvt_pk LOADB (r11/r12): prologue ~100 insts/wave.
//  - NEW: activation/cell math restructured over f32x2 pairs -> v_pk_*_f32
//    (2 f32/inst; exp/rcp stay scalar).  Same ops, same order, same numerics;
//    ~12-15% VALU-issue cut if pk forms, identical scalar code if not.
//  - Kept: pre-scaled gates (exp2 domain), cs-domain single-rcp cell, xs
//    float staging (0 bank conflicts), target-LSTM at blockIdx 0, slim
//    k_final, memset social.
__global__ __launch_bounds__(256, 2)
void k_neigh(
    const float* __restrict__ tgt,   // 15*1*2
    const float* __restrict__ oth,   // 15*N*2
    const int* __restrict__ mask,    // 15*N
    const float* __restrict__ W_ih,  // 256*2
    const float* __restrict__ b_ih,  // 256
    const float* __restrict__ W_hh,  // 256*64
    const float* __restrict__ b_hh,  // 256
    float* __restrict__ social,      // 16*64, pre-zeroed
    float* __restrict__ ht_out)      // 64 (target-LSTM final h)
{
  __shared__ __align__(16) unsigned short h2[2][NPB][HDIM];  // h as bf16
  __shared__ float xs[OBS][NPB][2];
  __shared__ float tht[HDIM];
  __shared__ float tgb[256];

  const int tid = threadIdx.x;

  if (blockIdx.x == 0) {
    // ---- target LSTM, fp32 exact (raw unscaled weights); dispatched FIRST
    // so it hides under the neighbor grid.  Block-uniform branch.
    const float bias = b_ih[tid] + b_hh[tid];
    const float wi0 = W_ih[tid * 2], wi1 = W_ih[tid * 2 + 1];
    const float4* Wr = (const float4*)&W_hh[tid * 64];
    if (tid < HDIM) tht[tid] = 0.0f;
    float ct = 0.0f;
    __syncthreads();
    for (int t = 0; t < OBS; ++t) {
      const float x0 = tgt[t * 2], x1 = tgt[t * 2 + 1];
      float acc = bias + x0 * wi0 + x1 * wi1;
#pragma unroll 4
      for (int k4 = 0; k4 < 16; ++k4) {
        const float4 wv = Wr[k4];
        const float4 hv = *(const float4*)&tht[k4 * 4];
        acc += wv.x * hv.x + wv.y * hv.y + wv.z * hv.z + wv.w * hv.w;
      }
      tgb[tid] = acc;
      __syncthreads();
      if (tid < HDIM) {
        const float cn =
            sigm(tgb[64 + tid]) * ct + sigm(tgb[tid]) * tanh_(tgb[128 + tid]);
        ct = cn;
        tht[tid] = sigm(tgb[192 + tid]) * tanh_(cn);
      }
      __syncthreads();
    }
    if (tid < HDIM) ht_out[tid] = tht[tid];
    return;
  }

  const int l = tid & 63;
  const int w = tid >> 6;   // wave id 0..3 -> owns gate-col slice w*16..w*16+15
  const int t15 = l & 15;
  const int g4 = l >> 4;
  const int n0 = (blockIdx.x - 1) * NPB;

  // stage xo for this block's 16 neighbors, all steps (coalesced, no tail)
  for (int i = tid; i < OBS * NPB * 2; i += 256) {
    ((float*)xs)[i] = oth[(i >> 5) * (NTOT * 2) + n0 * 2 + (i & 31)];
  }
  // zero h buffer 0
  for (int i = tid; i < NPB * HDIM / 2; i += 256) ((unsigned int*)h2[0])[i] = 0u;

  // persistent B fragments: W_hh^T slices for this wave's gate cols,
  // PRE-SCALED by the consuming activation's exp2 constant, single bf16 RNE
  // (lo plane dropped in r11, verified passing), packed via v_cvt_pk_bf16_f32.
  short8 Bhi0, Bhi1, Bhi2, Bhi3, Bhi4, Bhi5, Bhi6, Bhi7;
#define LOADB(q, kt, BH, SC)                                                  \
  {                                                                           \
    const float* wp = &W_hh[(q * 64 + w * 16 + t15) * 64 + kt * 32 + g4 * 8]; \
    u32x4 d;                                                                  \
    d.x = cvtpk_bf16(wp[0] * (SC), wp[1] * (SC));                             \
    d.y = cvtpk_bf16(wp[2] * (SC), wp[3] * (SC));                             \
    d.z = cvtpk_bf16(wp[4] * (SC), wp[5] * (SC));                             \
    d.w = cvtpk_bf16(wp[6] * (SC), wp[7] * (SC));                             \
    BH = __builtin_bit_cast(short8, d);                                       \
  }
  LOADB(0, 0, Bhi0, -KLOG2E)  LOADB(0, 1, Bhi1, -KLOG2E)
  LOADB(1, 0, Bhi2, -KLOG2E)  LOADB(1, 1, Bhi3, -KLOG2E)
  LOADB(2, 0, Bhi4, -KLOG2E2) LOADB(2, 1, Bhi5, -KLOG2E2)
  LOADB(3, 0, Bhi6, -KLOG2E)  LOADB(3, 1, Bhi7, -KLOG2E)
#undef LOADB

  // VALU acc-init constants, PRE-SCALED (gates live in the exp2 domain).
  float bias2[4], wih0[4], wih1[4];
#pragma unroll
  for (int q = 0; q < 4; ++q) {
    const float sc = (q == 2) ? -KLOG2E2 : -KLOG2E;
    const int g = q * 64 + w * 16 + t15;
    bias2[q] = (b_ih[g] + b_hh[g]) * sc;
    wih0[q] = W_ih[g * 2 + 0] * sc;
    wih1[q] = W_ih[g * 2 + 1] * sc;
  }

  // cs = -2log2e * c  (c starts at 0), held as two f32x2 pairs
  f32x2 cs01 = (f32x2){0.f, 0.f}, cs23 = (f32x2){0.f, 0.f};
  const float refx = tgt[14 * 2 + 0];
  const float refy = tgt[14 * 2 + 1];

  __syncthreads();

  for (int t = 0; t < OBS; ++t) {
    const int cur = t & 1, nxt = cur ^ 1;
    // A fragments: row t15, k-block (kt*4 + g4), direct bf16 LDS read
    short8 A0 = *(const short8*)&h2[cur][0][hidx(t15, g4)];
    short8 A1 = *(const short8*)&h2[cur][0][hidx(t15, 4 + g4)];

    // acc0 = -log2e*i, acc1 = -log2e*f, acc2 = -2log2e*g, acc3 = -log2e*o
    f32x4 acc0, acc1, acc2, acc3;
#pragma unroll
    for (int r = 0; r < 4; ++r) {
      const int nl = g4 * 4 + r;
      const float xa = xs[t][nl][0], xb = xs[t][nl][1];
      acc0[r] = bias2[0] + xa * wih0[0] + xb * wih1[0];
      acc1[r] = bias2[1] + xa * wih0[1] + xb * wih1[1];
      acc2[r] = bias2[2] + xa * wih0[2] + xb * wih1[2];
      acc3[r] = bias2[3] + xa * wih0[3] + xb * wih1[3];
    }
    acc0 = MFMA_BF16(A0, Bhi0, acc0, 0, 0, 0);
    acc1 = MFMA_BF16(A0, Bhi2, acc1, 0, 0, 0);
    acc2 = MFMA_BF16(A0, Bhi4, acc2, 0, 0, 0);
    acc3 = MFMA_BF16(A0, Bhi6, acc3, 0, 0, 0);
    acc0 = MFMA_BF16(A1, Bhi1, acc0, 0, 0, 0);
    acc1 = MFMA_BF16(A1, Bhi3, acc1, 0, 0, 0);
    acc2 = MFMA_BF16(A1, Bhi5, acc2, 0, 0, 0);
    acc3 = MFMA_BF16(A1, Bhi7, acc3, 0, 0, 0);

    // cs-domain fused cell on f32x2 pairs (A=1+ei, B=1+eg, C=1+ef):
    //   cs' = (cs*A*B + K2*(eg-1)*C) * rcp(A*B*C)   [= -2log2e * cn]
    //   ecn = exp2(cs')
    //   h   = (1-ecn) / ((1+eo)(1+ecn))             [= sig(o)*tanh(cn)]
#define CELL_PAIR(P, CS, H0, H1)                                              \
  {                                                                           \
    const f32x2 one = (f32x2){1.0f, 1.0f};                                    \
    f32x2 i2, f2, g2, o2;                                                     \
    i2.x = acc0[2 * P + 0]; i2.y = acc0[2 * P + 1];                           \
    f2.x = acc1[2 * P + 0]; f2.y = acc1[2 * P + 1];                           \
    g2.x = acc2[2 * P + 0]; g2.y = acc2[2 * P + 1];                           \
    o2.x = acc3[2 * P + 0]; o2.y = acc3[2 * P + 1];                           \
    const f32x2 ei = exp2v(i2), ef = exp2v(f2);                               \
    const f32x2 eg = exp2v(g2), eo = exp2v(o2);                               \
    const f32x2 A2 = one + ei, B2 = one + eg, C2 = one + ef;                  \
    const f32x2 AB = A2 * B2;                                                 \
    const f32x2 rr = rcpv(AB * C2);                                           \
    const f32x2 u2 = (eg - one) * C2;                                         \
    const f32x2 csn = (CS * AB + (f32x2){KLOG2E2, KLOG2E2} * u2) * rr;        \
    CS = csn;                                                                 \
    const f32x2 ecn = exp2v(csn);                                             \
    const f32x2 ro = rcpv((one + eo) * (one + ecn));                          \
    const f32x2 h2v = (one - ecn) * ro;                                       \
    H0 = h2v.x;                                                               \
    H1 = h2v.y;                                                               \
  }
    if (t < OBS - 1) {
      float hv0, hv1, hv2, hv3;
      CELL_PAIR(0, cs01, hv0, hv1)
      CELL_PAIR(1, cs23, hv2, hv3)
      const int col = w * 16 + t15;
      const int cb = col >> 3, ce = col & 7;
      h2[nxt][0][hidx(g4 * 4 + 0, cb) + ce] = f2bf(hv0);
      h2[nxt][0][hidx(g4 * 4 + 1, cb) + ce] = f2bf(hv1);
      h2[nxt][0][hidx(g4 * 4 + 2, cb) + ce] = f2bf(hv2);
      h2[nxt][0][hidx(g4 * 4 + 3, cb) + ce] = f2bf(hv3);
      __syncthreads();
    } else {
      // final step: compute h (fp32) and pool directly
      float hv[4];
      CELL_PAIR(0, cs01, hv[0], hv[1])
      CELL_PAIR(1, cs23, hv[2], hv[3])
#pragma unroll
      for (int r = 0; r < 4; ++r) {
        const int nl = g4 * 4 + r;
        const int gn = n0 + nl;
        const float rx = xs[OBS - 1][nl][0] - refx;
        const float ry = xs[OBS - 1][nl][1] - refy;
        bool ok = (fabsf(rx) <= 2.0f) && (fabsf(ry) <= 2.0f);
        const int cx = (int)truncf(rx) + 2;  // cw == 1.0
        const int cy = (int)truncf(ry) + 2;
        ok = ok && (cx >= 0) && (cx < 4) && (cy >= 0) && (cy < 4);
        if (ok && mask[(OBS - 1) * NTOT + gn] != 0)
          atomicAdd(&social[(cy * 4 + cx) * HDIM + w * 16 + t15], hv[r]);
      }
    }
#undef CELL_PAIR
  }
}

// Slim k_final (verified rounds 1-12): social MLP + readout only.
__global__ __launch_bounds__(512) void k_final(
    const float* __restrict__ W1, const float* __restrict__ b1,
    const float* __restrict__ W2, const float* __restrict__ b2,
    const float* __restrict__ Wc, const float* __restrict__ bc,
    const float* __restrict__ social, const float* __restrict__ ht_g,
    float* __restrict__ out)
{
  __shared__ float sv[1024];
  __shared__ float hid[64];
  __shared__ float comb[64];
  __shared__ float ht[64];

  const int tid = threadIdx.x;
  for (int i = tid; i < 1024; i += 512) sv[i] = social[i];
  if (tid < 64) ht[tid] = ht_g[tid];
  __syncthreads();

  const int wv = tid >> 6, ln = tid & 63;
  for (int o = wv; o < 64; o += 8) {
    float p = 0.0f;
#pragma unroll
    for (int it = 0; it < 16; ++it) {
      const int j = it * 64 + ln;
      p += sv[j] * W1[o * 1024 + j];
    }
#pragma unroll
    for (int off = 32; off > 0; off >>= 1) p += __shfl_down(p, off);
    if (ln == 0) hid[o] = fmaxf(p + b1[o], 0.0f);
  }
  __syncthreads();
  for (int o = wv; o < 64; o += 8) {
    float p = hid[ln] * W2[o * 64 + ln];
#pragma unroll
    for (int off = 32; off > 0; off >>= 1) p += __shfl_down(p, off);
    if (ln == 0) comb[o] = ht[o] + p + b2[o];
  }
  __syncthreads();
  if (wv < 2) {
    float p = comb[ln] * Wc[wv * 64 + ln];
#pragma unroll
    for (int off = 32; off > 0; off >>= 1) p += __shfl_down(p, off);
    if (ln == 0) out[wv] = p + bc[wv];
  }
}

extern "C" void kernel_launch(void* const* d_in, const int* in_sizes, int n_in,
                              void* d_out, int out_size, void* d_ws, size_t ws_size,
                              hipStream_t stream) {
  const float* tgt = (const float*)d_in[0];
  const float* oth = (const float*)d_in[1];
  const int* mask = (const int*)d_in[2];
  const float* W_ih = (const float*)d_in[3];
  const float* b_ih = (const float*)d_in[4];
  const float* W_hh = (const float*)d_in[5];
  const float* b_hh = (const float*)d_in[6];
  const float* W1 = (const float*)d_in[7];
  const float* b1 = (const float*)d_in[8];
  const float* W2 = (const float*)d_in[9];
  const float* b2 = (const float*)d_in[10];
  const float* Wc = (const float*)d_in[11];
  const float* bc = (const float*)d_in[12];
  float* social = (float*)d_ws;          // ws[0..1023]
  float* ht = social + 1024;             // ws[1024..1087] (target-LSTM h)
  float* out = (float*)d_out;

  // social zeroed via memset node (graph-capturable; harness reset() uses it)
  hipMemsetAsync(social, 0, 16 * 64 * sizeof(float), stream);
  hipLaunchKernelGGL(k_neigh, dim3(NBLK_N + 1), dim3(256), 0, stream,
                     tgt, oth, mask, W_ih, b_ih, W_hh, b_hh, social, ht);
  hipLaunchKernelGGL(k_final, dim3(1), dim3(512), 0, stream,
                     W1, b1, W2, b2, Wc, bc, social, ht, out);
}

// Round 14
// 122.784 us; speedup vs baseline: 1.0500x; 1.0425x over previous
//
#include <hip/hip_runtime.h>
#include <stdint.h>

#define OBS 15
#define NTOT 50000
#define HDIM 64
#define NPB 16               // neighbors per block (50000 = 3125 * 16, exact)
#define NBLK_N 3125          // neighbor blocks; blockIdx 0 runs the target LSTM
#define ZOFF (OBS * NPB * 8) // ushort index of the 16B zero slot in xbf

typedef __attribute__((ext_vector_type(8))) short short8;
typedef __attribute__((ext_vector_type(4))) float f32x4;
typedef __attribute__((ext_vector_type(4))) unsigned int u32x4;

#define KLOG2E 1.4426950408889634f   // log2(e)
#define KLOG2E2 2.8853900817779268f  // 2*log2(e)

static __device__ __forceinline__ unsigned short f2bf(float f) {
  unsigned u = __float_as_uint(f);
  u += 0x7fff + ((u >> 16) & 1);
  return (unsigned short)(u >> 16);
}
static __device__ __forceinline__ float bf2f(unsigned short b) {
  return __uint_as_float(((unsigned)b) << 16);
}

#if __has_builtin(__builtin_amdgcn_exp2f)
#define EXP2F(x) __builtin_amdgcn_exp2f(x)
#else
#define EXP2F(x) exp2f(x)
#endif
#if __has_builtin(__builtin_amdgcn_rcpf)
#define RCPF(x) __builtin_amdgcn_rcpf(x)
#else
#define RCPF(x) (1.0f / (x))
#endif

static __device__ __forceinline__ float sigm(float x) {
  return RCPF(1.0f + EXP2F(-KLOG2E * x));
}
static __device__ __forceinline__ float tanh_(float x) {
  return 2.0f * RCPF(1.0f + EXP2F(-KLOG2E2 * x)) - 1.0f;
}

// LDS ushort index: row r (0..15), 8-ushort block cb (0..7), swizzled.
static __device__ __forceinline__ int hidx(int r, int cb) {
  return r * 64 + ((cb ^ (r & 7)) << 3);
}

__global__ void k_zero(float* social) {
  social[threadIdx.x] = 0.0f;  // 1024 threads == 16*64 floats
}

#define MFMA_BF16 __builtin_amdgcn_mfma_f32_16x16x32_bf16

// ROUND-14: byte-exact resubmission of the ROUND-6 kernel — the session's
// best TIMED configuration (120.5 us).  Timed ledger (noise ±1 us within
// structure): r6=120.5 < r10=123.4 (16-MFMA+cs-domain) < r11-13=128-129
// (8-MFMA no-lo family, all launch-bounds and f32x2 variants).  Profiled
// k_neigh IMPROVED down that path (119.6->112) while timed worsened — an
// unexplained profiled/timed inversion; the gold metric (timed) arbitrates.
// Every arc beyond this config was measured timed-non-positive: occupancy
// (r8/r9/r12), intra-wave ILP (r5), transposed MFMA (r1/r2), TAB prep (r7),
// no-lo W (r11), f32x2 packing (r13).
__global__ __launch_bounds__(256, 2)
void k_neigh(
    const float* __restrict__ tgt,   // 15*1*2
    const float* __restrict__ oth,   // 15*N*2
    const int* __restrict__ mask,    // 15*N
    const float* __restrict__ W_ih,  // 256*2
    const float* __restrict__ b_ih,  // 256
    const float* __restrict__ W_hh,  // 256*64
    const float* __restrict__ b_hh,  // 256
    float* __restrict__ social,      // 16*64, pre-zeroed
    float* __restrict__ ht_out)      // 64 (target-LSTM final h)
{
  __shared__ __align__(16) unsigned short h2[2][NPB][HDIM];  // h as bf16
  // per (t,n): 8 ushorts {x0hi,x0hi,x0lo,x1hi,x1hi,x1lo,1,1} + 16B zero slot
  __shared__ __align__(16) unsigned short xbf[ZOFF + 8];
  __shared__ float xs14[NPB][2];
  __shared__ float tht[HDIM];
  __shared__ float tgb[256];

  const int tid = threadIdx.x;

  if (blockIdx.x == 0) {
    // ---- target LSTM, fp32 exact (raw unscaled weights); dispatched FIRST
    // so it hides under the neighbor grid.  Block-uniform branch.
    const float bias = b_ih[tid] + b_hh[tid];
    const float wi0 = W_ih[tid * 2], wi1 = W_ih[tid * 2 + 1];
    const float4* Wr = (const float4*)&W_hh[tid * 64];
    if (tid < HDIM) tht[tid] = 0.0f;
    float ct = 0.0f;
    __syncthreads();
    for (int t = 0; t < OBS; ++t) {
      const float x0 = tgt[t * 2], x1 = tgt[t * 2 + 1];
      float acc = bias + x0 * wi0 + x1 * wi1;
#pragma unroll 4
      for (int k4 = 0; k4 < 16; ++k4) {
        const float4 wv = Wr[k4];
        const float4 hv = *(const float4*)&tht[k4 * 4];
        acc += wv.x * hv.x + wv.y * hv.y + wv.z * hv.z + wv.w * hv.w;
      }
      tgb[tid] = acc;
      __syncthreads();
      if (tid < HDIM) {
        const float cn =
            sigm(tgb[64 + tid]) * ct + sigm(tgb[tid]) * tanh_(tgb[128 + tid]);
        ct = cn;
        tht[tid] = sigm(tgb[192 + tid]) * tanh_(cn);
      }
      __syncthreads();
    }
    if (tid < HDIM) ht_out[tid] = tht[tid];
    return;
  }

  const int l = tid & 63;
  const int w = tid >> 6;   // wave id 0..3 -> owns gate-col slice w*16..w*16+15
  const int t15 = l & 15;
  const int g4 = l >> 4;
  const int n0 = (blockIdx.x - 1) * NPB;

  // ---- stage x hi/lo MFMA table + last-step raw positions (240 items) ----
  if (tid < OBS * NPB) {
    const int t = tid >> 4, n = tid & 15;
    const int gn = n0 + n;
    const float x0 = oth[(t * NTOT + gn) * 2 + 0];
    const float x1 = oth[(t * NTOT + gn) * 2 + 1];
    const unsigned short xh0 = f2bf(x0);
    const unsigned short xl0 = f2bf(x0 - bf2f(xh0));
    const unsigned short xh1 = f2bf(x1);
    const unsigned short xl1 = f2bf(x1 - bf2f(xh1));
    u32x4 d;
    d.x = (unsigned)xh0 | ((unsigned)xh0 << 16);  // k0=x0hi k1=x0hi
    d.y = (unsigned)xl0 | ((unsigned)xh1 << 16);  // k2=x0lo k3=x1hi
    d.z = (unsigned)xh1 | ((unsigned)xl1 << 16);  // k4=x1hi k5=x1lo
    d.w = 0x3F803F80u;                            // k6=1    k7=1
    *(u32x4*)&xbf[tid * 8] = d;
    if (t == OBS - 1) { xs14[n][0] = x0; xs14[n][1] = x1; }
  }
  if (tid == 255) {
    u32x4 zz = {0u, 0u, 0u, 0u};
    *(u32x4*)&xbf[ZOFF] = zz;
  }
  // zero h buffer 0
  for (int i = tid; i < NPB * HDIM / 2; i += 256) ((unsigned int*)h2[0])[i] = 0u;

  // persistent B fragments: W_hh^T slices for this wave's gate cols, PRE-
  // SCALED by the exp2 constant of the consuming activation, RNE hi/lo split.
  short8 Bhi0, Bhi1, Bhi2, Bhi3, Bhi4, Bhi5, Bhi6, Bhi7;
  short8 Blo0, Blo1, Blo2, Blo3, Blo4, Blo5, Blo6, Blo7;
#define LOADB(q, kt, BH, BL, SC)                                              \
  {                                                                           \
    const float* wp = &W_hh[(q * 64 + w * 16 + t15) * 64 + kt * 32 + g4 * 8]; \
    _Pragma("unroll") for (int j = 0; j < 8; ++j) {                           \
      float wv = wp[j] * (SC);                                                \
      unsigned short hi = f2bf(wv);                                           \
      unsigned short lo = f2bf(wv - bf2f(hi));                                \
      BH[j] = (short)hi;                                                      \
      BL[j] = (short)lo;                                                      \
    }                                                                         \
  }
  LOADB(0, 0, Bhi0, Blo0, -KLOG2E)  LOADB(0, 1, Bhi1, Blo1, -KLOG2E)
  LOADB(1, 0, Bhi2, Blo2, -KLOG2E)  LOADB(1, 1, Bhi3, Blo3, -KLOG2E)
  LOADB(2, 0, Bhi4, Blo4, -KLOG2E2) LOADB(2, 1, Bhi5, Blo5, -KLOG2E2)
  LOADB(3, 0, Bhi6, Blo6, -KLOG2E)  LOADB(3, 1, Bhi7, Blo7, -KLOG2E)
#undef LOADB

  // ---- B_x fragments: W_ih + bias as MFMA B-operand, same pre-scaling.
  // k-slots pair with xbf rows: dot vs {x0hi,x0hi,x0lo,x1hi,x1hi,x1lo,1,1}
  // = sc*(w0*x0 + w1*x1 + bias) (hi*hi+hi*lo+lo*hi each) — proven pairing.
  short8 BX0, BX1, BX2, BX3;
  {
    u32x4 z4 = {0u, 0u, 0u, 0u};
    BX0 = BX1 = BX2 = BX3 = __builtin_bit_cast(short8, z4);
    if (g4 == 0) {
#pragma unroll
      for (int q = 0; q < 4; ++q) {
        const float sc = (q == 2) ? -KLOG2E2 : -KLOG2E;
        const int G = q * 64 + w * 16 + t15;
        const float w0 = W_ih[G * 2 + 0] * sc, w1 = W_ih[G * 2 + 1] * sc;
        const float bs = (b_ih[G] + b_hh[G]) * sc;
        const unsigned short w0h = f2bf(w0), w0l = f2bf(w0 - bf2f(w0h));
        const unsigned short w1h = f2bf(w1), w1l = f2bf(w1 - bf2f(w1h));
        const unsigned short bh = f2bf(bs), bl = f2bf(bs - bf2f(bh));
        u32x4 d;
        d.x = (unsigned)w0h | ((unsigned)w0l << 16);
        d.y = (unsigned)w0h | ((unsigned)w1h << 16);
        d.z = (unsigned)w1l | ((unsigned)w1h << 16);
        d.w = (unsigned)bh | ((unsigned)bl << 16);
        const short8 v = __builtin_bit_cast(short8, d);
        if (q == 0) BX0 = v;
        else if (q == 1) BX1 = v;
        else if (q == 2) BX2 = v;
        else BX3 = v;
      }
    }
  }

  // A_x read offset: g4==0 lanes walk the xbf table, others broadcast-read
  // the zero slot (uniform address -> no conflict).
  int xo = (g4 == 0) ? (t15 * 8) : ZOFF;
  const int xst = (g4 == 0) ? (NPB * 8) : 0;

  f32x4 c = (f32x4){0.f, 0.f, 0.f, 0.f};
  const float refx = tgt[14 * 2 + 0];
  const float refy = tgt[14 * 2 + 1];

  __syncthreads();

  for (int t = 0; t < OBS; ++t) {
    const int cur = t & 1, nxt = cur ^ 1;
    // A_x fragment first (chain head), then h A-fragments
    const short8 Ax = *(const short8*)&xbf[xo];
    short8 A0 = *(const short8*)&h2[cur][0][hidx(t15, g4)];
    short8 A1 = *(const short8*)&h2[cur][0][hidx(t15, 4 + g4)];
    xo += xst;

    // acc0 = -log2e*i, acc1 = -log2e*f, acc2 = -2log2e*g, acc3 = -log2e*o
    const f32x4 z = (f32x4){0.f, 0.f, 0.f, 0.f};
    f32x4 acc0 = MFMA_BF16(Ax, BX0, z, 0, 0, 0);
    f32x4 acc1 = MFMA_BF16(Ax, BX1, z, 0, 0, 0);
    f32x4 acc2 = MFMA_BF16(Ax, BX2, z, 0, 0, 0);
    f32x4 acc3 = MFMA_BF16(Ax, BX3, z, 0, 0, 0);
    acc0 = MFMA_BF16(A0, Bhi0, acc0, 0, 0, 0);
    acc1 = MFMA_BF16(A0, Bhi2, acc1, 0, 0, 0);
    acc2 = MFMA_BF16(A0, Bhi4, acc2, 0, 0, 0);
    acc3 = MFMA_BF16(A0, Bhi6, acc3, 0, 0, 0);
    acc0 = MFMA_BF16(A1, Bhi1, acc0, 0, 0, 0);
    acc1 = MFMA_BF16(A1, Bhi3, acc1, 0, 0, 0);
    acc2 = MFMA_BF16(A1, Bhi5, acc2, 0, 0, 0);
    acc3 = MFMA_BF16(A1, Bhi7, acc3, 0, 0, 0);
    acc0 = MFMA_BF16(A0, Blo0, acc0, 0, 0, 0);
    acc1 = MFMA_BF16(A0, Blo2, acc1, 0, 0, 0);
    acc2 = MFMA_BF16(A0, Blo4, acc2, 0, 0, 0);
    acc3 = MFMA_BF16(A0, Blo6, acc3, 0, 0, 0);
    acc0 = MFMA_BF16(A1, Blo1, acc0, 0, 0, 0);
    acc1 = MFMA_BF16(A1, Blo3, acc1, 0, 0, 0);
    acc2 = MFMA_BF16(A1, Blo5, acc2, 0, 0, 0);
    acc3 = MFMA_BF16(A1, Blo7, acc3, 0, 0, 0);

    // fused-rcp LSTM cell: ei..eo are exp2 of pre-scaled gates.
    //   sig(f)          = 1/(1+ef)
    //   sig(i)*tanh(g)  = (1-eg)/((1+ei)(1+eg))
    //   sig(o)*tanh(cn) = (1-ecn)/((1+eo)(1+ecn))
    if (t < OBS - 1) {
#pragma unroll
      for (int r = 0; r < 4; ++r) {
        const float ei = EXP2F(acc0[r]);
        const float ef = EXP2F(acc1[r]);
        const float eg = EXP2F(acc2[r]);
        const float eo = EXP2F(acc3[r]);
        const float sf = RCPF(1.0f + ef);
        const float rig = RCPF((1.0f + ei) * (1.0f + eg));
        const float cn = c[r] * sf + (1.0f - eg) * rig;
        c[r] = cn;
        const float ecn = EXP2F(-KLOG2E2 * cn);
        const float ro = RCPF((1.0f + eo) * (1.0f + ecn));
        const float h = (1.0f - ecn) * ro;
        const int n = g4 * 4 + r;
        const int col = w * 16 + t15;
        h2[nxt][0][hidx(n, col >> 3) + (col & 7)] = f2bf(h);
      }
      __syncthreads();
    } else {
      // final step: compute h (fp32) and pool directly
#pragma unroll
      for (int r = 0; r < 4; ++r) {
        const float ei = EXP2F(acc0[r]);
        const float ef = EXP2F(acc1[r]);
        const float eg = EXP2F(acc2[r]);
        const float eo = EXP2F(acc3[r]);
        const float sf = RCPF(1.0f + ef);
        const float rig = RCPF((1.0f + ei) * (1.0f + eg));
        const float cn = c[r] * sf + (1.0f - eg) * rig;
        const float ecn = EXP2F(-KLOG2E2 * cn);
        const float ro = RCPF((1.0f + eo) * (1.0f + ecn));
        const float h = (1.0f - ecn) * ro;
        const int nl = g4 * 4 + r;
        const int gn = n0 + nl;
        const float rx = xs14[nl][0] - refx;
        const float ry = xs14[nl][1] - refy;
        bool ok = (fabsf(rx) <= 2.0f) && (fabsf(ry) <= 2.0f);
        const int cx = (int)truncf(rx) + 2;  // cw == 1.0
        const int cy = (int)truncf(ry) + 2;
        ok = ok && (cx >= 0) && (cx < 4) && (cy >= 0) && (cy < 4);
        if (ok && mask[(OBS - 1) * NTOT + gn] != 0)
          atomicAdd(&social[(cy * 4 + cx) * HDIM + w * 16 + t15], h);
      }
    }
  }
}

// Slim k_final (verified rounds 1-13): social MLP + readout only.
__global__ __launch_bounds__(512) void k_final(
    const float* __restrict__ W1, const float* __restrict__ b1,
    const float* __restrict__ W2, const float* __restrict__ b2,
    const float* __restrict__ Wc, const float* __restrict__ bc,
    const float* __restrict__ social, const float* __restrict__ ht_g,
    float* __restrict__ out)
{
  __shared__ float sv[1024];
  __shared__ float hid[64];
  __shared__ float comb[64];
  __shared__ float ht[64];

  const int tid = threadIdx.x;
  for (int i = tid; i < 1024; i += 512) sv[i] = social[i];
  if (tid < 64) ht[tid] = ht_g[tid];
  __syncthreads();

  const int wv = tid >> 6, ln = tid & 63;
  for (int o = wv; o < 64; o += 8) {
    float p = 0.0f;
#pragma unroll
    for (int it = 0; it < 16; ++it) {
      const int j = it * 64 + ln;
      p += sv[j] * W1[o * 1024 + j];
    }
#pragma unroll
    for (int off = 32; off > 0; off >>= 1) p += __shfl_down(p, off);
    if (ln == 0) hid[o] = fmaxf(p + b1[o], 0.0f);
  }
  __syncthreads();
  for (int o = wv; o < 64; o += 8) {
    float p = hid[ln] * W2[o * 64 + ln];
#pragma unroll
    for (int off = 32; off > 0; off >>= 1) p += __shfl_down(p, off);
    if (ln == 0) comb[o] = ht[o] + p + b2[o];
  }
  __syncthreads();
  if (wv < 2) {
    float p = comb[ln] * Wc[wv * 64 + ln];
#pragma unroll
    for (int off = 32; off > 0; off >>= 1) p += __shfl_down(p, off);
    if (ln == 0) out[wv] = p + bc[wv];
  }
}

extern "C" void kernel_launch(void* const* d_in, const int* in_sizes, int n_in,
                              void* d_out, int out_size, void* d_ws, size_t ws_size,
                              hipStream_t stream) {
  const float* tgt = (const float*)d_in[0];
  const float* oth = (const float*)d_in[1];
  const int* mask = (const int*)d_in[2];
  const float* W_ih = (const float*)d_in[3];
  const float* b_ih = (const float*)d_in[4];
  const float* W_hh = (const float*)d_in[5];
  const float* b_hh = (const float*)d_in[6];
  const float* W1 = (const float*)d_in[7];
  const float* b1 = (const float*)d_in[8];
  const float* W2 = (const float*)d_in[9];
  const float* b2 = (const float*)d_in[10];
  const float* Wc = (const float*)d_in[11];
  const float* bc = (const float*)d_in[12];
  float* social = (float*)d_ws;          // ws[0..1023]
  float* ht = social + 1024;             // ws[1024..1087] (target-LSTM h)
  float* out = (float*)d_out;

  hipLaunchKernelGGL(k_zero, dim3(1), dim3(1024), 0, stream, social);
  hipLaunchKernelGGL(k_neigh, dim3(NBLK_N + 1), dim3(256), 0, stream,
                     tgt, oth, mask, W_ih, b_ih, W_hh, b_hh, social, ht);
  hipLaunchKernelGGL(k_final, dim3(1), dim3(512), 0, stream,
                     W1, b1, W2, b2, Wc, bc, social, ht, out);
}